// Round 9
// baseline (448.540 us; speedup 1.0000x reference)
//
#include <hip/hip_runtime.h>

#define NN 100000
#define NE 1600000

// ---- workspace layout (bytes) ----
// persistent
static constexpr size_t OFF_H0   = 0;                     // [N,64] f32
static constexpr size_t OFF_H1   = 25600000;              // [N,64] f32
static constexpr size_t OFF_H2   = 51200000;              // [N,64] f32
static constexpr size_t OFF_CSRP = 76800000;              // [E] (int src, f32 w) pairs = 12.8MB
static constexpr size_t OFF_ROW  = 89600000;              // [N+1] i32
static constexpr size_t OFF_NRM  = 90000064;              // [N] f32
static constexpr size_t OFF_INVD = 90400064;              // [N] f32
static constexpr size_t OFF_HH   = 90800064;              // [N] f32
static constexpr size_t OFF_Q0   = 91200064;              // [N] f32
static constexpr size_t OFF_Q1   = 91600064;              // [N] f32
static constexpr size_t OFF_SCR  = 92000064;              // union scratch base
// scratch A (CSR build, dead after merge)
static constexpr size_t OFF_SUBDEG = OFF_SCR;             // [8N] i32
static constexpr size_t OFF_SUBROW = OFF_SCR + 3200000;   // [8N+1] i32
static constexpr size_t OFF_SUBCUR = OFF_SCR + 6400080;   // [8N] i32
static constexpr size_t OFF_SUBCSR = OFF_SCR + 9600080;   // [E] i32
static constexpr size_t OFF_DEG    = OFF_SCR + 16000080;  // [N] i32
static constexpr size_t OFF_BSUM   = OFF_SCR + 16400080;  // [<=2048] i32
static constexpr size_t OFF_BOFF   = OFF_SCR + 16408272;  // [<=2048] i32
// scratch B (layers onward)
static constexpr size_t OFF_PARTF = OFF_SCR;              // [2048,256] f64 = 4MB
static constexpr size_t OFF_MID   = OFF_SCR + 4194304;    // [32,256] f64

// ---- CSR build: XCD-local sub-CSRs ----
__global__ void hist8_kernel(const int* __restrict__ dst, int* __restrict__ subdeg) {
    int e = blockIdx.x * 256 + threadIdx.x;
    int g = blockIdx.x & 7;
    if (e < NE) {
        int d = __builtin_nontemporal_load(&dst[e]);
        atomicAdd(&subdeg[g * NN + d], 1);
    }
}

__global__ void degnorm_kernel(const int* __restrict__ subdeg, int* __restrict__ deg,
                               float* __restrict__ nrm, float* __restrict__ invd) {
    int n = blockIdx.x * 256 + threadIdx.x;
    if (n < NN) {
        int d = 0;
        #pragma unroll
        for (int g = 0; g < 8; ++g) d += subdeg[g * NN + n];
        deg[n] = d;
        float df = (float)max(d, 1);
        nrm[n]  = 1.0f / sqrtf(df);
        invd[n] = 1.0f / df;
    }
}

// ---- generic 3-stage exclusive scan (512-thread blocks) ----
__global__ void scanA_kernel(const int* __restrict__ in, int n, int* __restrict__ outloc,
                             int* __restrict__ bsum) {
    __shared__ int wsum[8], wexcl[8];
    int tid = threadIdx.x, lane = tid & 63, wid = tid >> 6;
    int i = blockIdx.x * 512 + tid;
    int v = (i < n) ? in[i] : 0;
    int x = v;
    #pragma unroll
    for (int off = 1; off < 64; off <<= 1) {
        int y = __shfl_up(x, off);
        if (lane >= off) x += y;
    }
    if (lane == 63) wsum[wid] = x;
    __syncthreads();
    if (tid == 0) {
        int c = 0;
        #pragma unroll
        for (int j = 0; j < 8; ++j) { wexcl[j] = c; c += wsum[j]; }
        bsum[blockIdx.x] = c;
    }
    __syncthreads();
    if (i < n) outloc[i] = (x - v) + wexcl[wid];
}

__global__ void scanB_kernel(const int* __restrict__ bsum, int nb, int* __restrict__ boff,
                             int* __restrict__ total_out) {
    __shared__ int wsum[8], wexcl[8];
    __shared__ int carry;
    int tid = threadIdx.x, lane = tid & 63, wid = tid >> 6;
    if (tid == 0) carry = 0;
    __syncthreads();
    for (int base = 0; base < nb; base += 512) {
        int i = base + tid;
        int v = (i < nb) ? bsum[i] : 0;
        int x = v;
        #pragma unroll
        for (int off = 1; off < 64; off <<= 1) {
            int y = __shfl_up(x, off);
            if (lane >= off) x += y;
        }
        if (lane == 63) wsum[wid] = x;
        __syncthreads();
        if (tid == 0) {
            int c = 0;
            #pragma unroll
            for (int j = 0; j < 8; ++j) { wexcl[j] = c; c += wsum[j]; }
        }
        __syncthreads();
        if (i < nb) boff[i] = carry + wexcl[wid] + (x - v);
        __syncthreads();
        if (tid == 0) carry += wexcl[7] + wsum[7];
        __syncthreads();
    }
    if (tid == 0) *total_out = carry;
}

__global__ void scanC_kernel(int* __restrict__ outloc, const int* __restrict__ boff, int n,
                             int* __restrict__ copy) {
    int i = blockIdx.x * 512 + threadIdx.x;
    if (i < n) {
        int r = outloc[i] + boff[blockIdx.x];
        outloc[i] = r;
        if (copy) copy[i] = r;
    }
}

__global__ void fillB_kernel(const int* __restrict__ src, const int* __restrict__ dst,
                             int* __restrict__ subcur, int* __restrict__ subcsr) {
    int e = blockIdx.x * 256 + threadIdx.x;
    int g = blockIdx.x & 7;
    if (e < NE) {
        int d = __builtin_nontemporal_load(&dst[e]);
        int s = __builtin_nontemporal_load(&src[e]);
        int p = atomicAdd(&subcur[g * NN + d], 1);
        subcsr[p] = s;
    }
}

// output-centric merge: thread per CSR slot p, binary search node, writes (src, w) pair
__global__ void merge_bs_kernel(const int* __restrict__ row_off, const int* __restrict__ subrow,
                                const int* __restrict__ subcur, const int* __restrict__ subcsr,
                                const float* __restrict__ nrm, int* __restrict__ csrp) {
    int p = blockIdx.x * 256 + threadIdx.x;
    if (p >= NE) return;
    int lo = 0, hi = NN;   // row_off[NN] = NE
    while (lo + 1 < hi) {
        int mid = (lo + hi) >> 1;
        if (row_off[mid] <= p) lo = mid; else hi = mid;
    }
    int n = lo;
    int local = p - row_off[n];
    int s = 0;
    #pragma unroll
    for (int g = 0; g < 8; ++g) {
        int base = g * NN + n;
        int st = subrow[base];
        int len = subcur[base] - st;
        if (local < len) { s = subcsr[st + local]; break; }
        local -= len;
    }
    int2 pr;
    pr.x = s;
    pr.y = __float_as_int(nrm[s]);
    ((int2*)csrp)[p] = pr;
}

// ---- embed: h0 = x @ W_emb.T + b_emb (rolled k-loop, no spill) ----
#define FMA4(a_, s_, v_)                        \
    a_.x = fmaf((s_), (v_).x, a_.x);            \
    a_.y = fmaf((s_), (v_).y, a_.y);            \
    a_.z = fmaf((s_), (v_).z, a_.z);            \
    a_.w = fmaf((s_), (v_).w, a_.w);

__global__ void embed_kernel(const float* __restrict__ x, const float* __restrict__ W,
                             const float* __restrict__ bias, float* __restrict__ h) {
    __shared__ __align__(16) float xs[64 * 68];
    __shared__ __align__(16) float Wt[64 * 68];   // Wt[k][d] = W[d][k]
    const int tid = threadIdx.x;
    for (int i = tid; i < 64 * 64; i += 256) {
        int d = i >> 6, k = i & 63;
        Wt[k * 68 + d] = W[i];
    }
    const int base = blockIdx.x * 64;
    for (int i = tid; i < 64 * 16; i += 256) {
        int r = i >> 4, c4 = i & 15;
        float4 v = make_float4(0.f, 0.f, 0.f, 0.f);
        if (base + r < NN) v = ((const float4*)x)[(size_t)(base + r) * 16 + c4];
        *(float4*)&xs[r * 68 + c4 * 4] = v;
    }
    __syncthreads();
    const int tn = tid >> 4;
    const int td = tid & 15;
    const float* xr0 = &xs[(tn * 4 + 0) * 68];
    const float* xr1 = &xs[(tn * 4 + 1) * 68];
    const float* xr2 = &xs[(tn * 4 + 2) * 68];
    const float* xr3 = &xs[(tn * 4 + 3) * 68];
    float4 a0 = make_float4(0.f, 0.f, 0.f, 0.f);
    float4 a1 = a0, a2 = a0, a3 = a0;
    #pragma unroll 1
    for (int k0 = 0; k0 < 64; k0 += 4) {
        float4 xa0 = *(const float4*)&xr0[k0];
        float4 xa1 = *(const float4*)&xr1[k0];
        float4 xa2 = *(const float4*)&xr2[k0];
        float4 xa3 = *(const float4*)&xr3[k0];
        float4 w0 = *(const float4*)&Wt[(k0 + 0) * 68 + td * 4];
        float4 w1 = *(const float4*)&Wt[(k0 + 1) * 68 + td * 4];
        float4 w2 = *(const float4*)&Wt[(k0 + 2) * 68 + td * 4];
        float4 w3 = *(const float4*)&Wt[(k0 + 3) * 68 + td * 4];
        FMA4(a0, xa0.x, w0); FMA4(a1, xa1.x, w0); FMA4(a2, xa2.x, w0); FMA4(a3, xa3.x, w0);
        FMA4(a0, xa0.y, w1); FMA4(a1, xa1.y, w1); FMA4(a2, xa2.y, w1); FMA4(a3, xa3.y, w1);
        FMA4(a0, xa0.z, w2); FMA4(a1, xa1.z, w2); FMA4(a2, xa2.z, w2); FMA4(a3, xa3.z, w2);
        FMA4(a0, xa0.w, w3); FMA4(a1, xa1.w, w3); FMA4(a2, xa2.w, w3); FMA4(a3, xa3.w, w3);
    }
    float4 bb = ((const float4*)bias)[td];
    a0.x += bb.x; a0.y += bb.y; a0.z += bb.z; a0.w += bb.w;
    a1.x += bb.x; a1.y += bb.y; a1.z += bb.z; a1.w += bb.w;
    a2.x += bb.x; a2.y += bb.y; a2.z += bb.z; a2.w += bb.w;
    a3.x += bb.x; a3.y += bb.y; a3.z += bb.z; a3.w += bb.w;
    int n0 = base + tn * 4;
    if (n0 + 0 < NN) ((float4*)h)[(size_t)(n0 + 0) * 16 + td] = a0;
    if (n0 + 1 < NN) ((float4*)h)[(size_t)(n0 + 1) * 16 + td] = a1;
    if (n0 + 2 < NN) ((float4*)h)[(size_t)(n0 + 2) * 16 + td] = a2;
    if (n0 + 3 < NN) ((float4*)h)[(size_t)(n0 + 3) * 16 + td] = a3;
}

// quad gather: 16 lanes per row (dwordx4), 4 rows per wave-step, 8-edge main loop.
// lane = (sub<<4)|d4; returns the full c-row quad for dims d4*4..d4*4+3 (all subs equal).
__device__ __forceinline__ float4 gather_quad(const float* __restrict__ h,
                                              const int* __restrict__ csrp,
                                              int start, int end, int sub, int d4) {
    float4 A = make_float4(0.f, 0.f, 0.f, 0.f);
    float4 B = A;
    const int2* pp = (const int2*)csrp;
    int i = start;
    for (; i + 8 <= end; i += 8) {
        int2 p0 = pp[i + sub];
        int2 p1 = pp[i + 4 + sub];
        float4 u = *(const float4*)&h[(size_t)p0.x * 64 + d4 * 4];
        float4 v = *(const float4*)&h[(size_t)p1.x * 64 + d4 * 4];
        float w0 = __int_as_float(p0.y);
        float w1 = __int_as_float(p1.y);
        FMA4(A, w0, u);
        FMA4(B, w1, v);
    }
    for (; i < end; i += 4) {
        int e = i + sub;
        int ec = min(e, end - 1);
        int2 p0 = pp[ec];
        float w0 = (e < end) ? __int_as_float(p0.y) : 0.f;
        float4 u = *(const float4*)&h[(size_t)p0.x * 64 + d4 * 4];
        FMA4(A, w0, u);
    }
    A.x += B.x; A.y += B.y; A.z += B.z; A.w += B.w;
    A.x += __shfl_xor(A.x, 16); A.y += __shfl_xor(A.y, 16);
    A.z += __shfl_xor(A.z, 16); A.w += __shfl_xor(A.w, 16);
    A.x += __shfl_xor(A.x, 32); A.y += __shfl_xor(A.y, 32);
    A.z += __shfl_xor(A.z, 32); A.w += __shfl_xor(A.w, 32);
    return A;
}

// layer0: gather c0 (not stored); h1 = h0 + c0*nm; hh=||h0||^2*nm^2, q0=||c0||^2
__global__ void layer0_kernel(const float* __restrict__ h0, const int* __restrict__ row_off,
                              const int* __restrict__ csrp, const float* __restrict__ nrm,
                              const float* __restrict__ invd, float* __restrict__ h1,
                              float* __restrict__ hh, float* __restrict__ q0) {
    int wg = __builtin_amdgcn_readfirstlane((blockIdx.x * 256 + threadIdx.x) >> 6);
    int lane = threadIdx.x & 63;
    if (wg >= NN) return;
    int sub = lane >> 4, d4 = lane & 15;
    float4 cq = gather_quad(h0, csrp, row_off[wg], row_off[wg + 1], sub, d4);
    float id = invd[wg], nm = nrm[wg];
    cq.x *= id; cq.y *= id; cq.z *= id; cq.w *= id;
    float4 hv = ((const float4*)(h0 + (size_t)wg * 64))[d4];
    float4 o;
    o.x = fmaf(cq.x, nm, hv.x); o.y = fmaf(cq.y, nm, hv.y);
    o.z = fmaf(cq.z, nm, hv.z); o.w = fmaf(cq.w, nm, hv.w);
    if (sub == 0) ((float4*)(h1 + (size_t)wg * 64))[d4] = o;
    float nm2 = nm * nm;
    float sh = (hv.x * hv.x + hv.y * hv.y + hv.z * hv.z + hv.w * hv.w) * nm2;
    float sc = cq.x * cq.x + cq.y * cq.y + cq.z * cq.z + cq.w * cq.w;
    #pragma unroll
    for (int off = 8; off >= 1; off >>= 1) {
        sh += __shfl_xor(sh, off);
        sc += __shfl_xor(sc, off);
    }
    if (lane == 0) { hh[wg] = sh; q0[wg] = sc; }
}

// layer1: gather c1 (not stored); h2 = h1 + c1*nm; q1=||c1||^2
__global__ void layer1_kernel(const float* __restrict__ h1, const int* __restrict__ row_off,
                              const int* __restrict__ csrp, const float* __restrict__ nrm,
                              const float* __restrict__ invd, float* __restrict__ h2,
                              float* __restrict__ q1) {
    int wg = __builtin_amdgcn_readfirstlane((blockIdx.x * 256 + threadIdx.x) >> 6);
    int lane = threadIdx.x & 63;
    if (wg >= NN) return;
    int sub = lane >> 4, d4 = lane & 15;
    float4 cq = gather_quad(h1, csrp, row_off[wg], row_off[wg + 1], sub, d4);
    float id = invd[wg], nm = nrm[wg];
    cq.x *= id; cq.y *= id; cq.z *= id; cq.w *= id;
    float4 hv = ((const float4*)(h1 + (size_t)wg * 64))[d4];
    float4 o;
    o.x = fmaf(cq.x, nm, hv.x); o.y = fmaf(cq.y, nm, hv.y);
    o.z = fmaf(cq.z, nm, hv.z); o.w = fmaf(cq.w, nm, hv.w);
    if (sub == 0) ((float4*)(h2 + (size_t)wg * 64))[d4] = o;
    float sc = cq.x * cq.x + cq.y * cq.y + cq.z * cq.z + cq.w * cq.w;
    #pragma unroll
    for (int off = 8; off >= 1; off >>= 1) sc += __shfl_xor(sc, off);
    if (lane == 0) q1[wg] = sc;
}

// layer2 fused with weighted colsum: gather c2; g-chain; recover c0,c1 from h diffs;
// f64 double4 partial colsums per lane, LDS deposit from sub==0 lanes.
__global__ void layer2_fused(const float* __restrict__ h0, const float* __restrict__ h1,
                             const float* __restrict__ h2, const int* __restrict__ row_off,
                             const int* __restrict__ csrp, const float* __restrict__ nrm,
                             const float* __restrict__ invd, const float* __restrict__ hh,
                             const float* __restrict__ q0, const float* __restrict__ q1,
                             double* __restrict__ partialF) {
    __shared__ double lds[256];
    int tid = threadIdx.x, lane = tid & 63, wid = tid >> 6;
    int sub = lane >> 4, d4 = lane & 15;
    double4 A0 = {0.0, 0.0, 0.0, 0.0};
    double4 A1 = A0, A2 = A0, A3 = A0;
    const float EPS = 1e-12f;
    for (int nb = blockIdx.x * 4 + wid; nb < NN; nb += gridDim.x * 4) {
        int wg = __builtin_amdgcn_readfirstlane(nb);
        float4 cq = gather_quad(h2, csrp, row_off[wg], row_off[wg + 1], sub, d4);
        float id = invd[wg];
        cq.x *= id; cq.y *= id; cq.z *= id; cq.w *= id;
        float sc = cq.x * cq.x + cq.y * cq.y + cq.z * cq.z + cq.w * cq.w;
        #pragma unroll
        for (int off = 8; off >= 1; off >>= 1) sc += __shfl_xor(sc, off);
        float n0s = hh[wg] + q0[wg];
        float s0 = fmaxf(sqrtf(n0s), EPS);
        float r1s = n0s / (s0 * s0) + q1[wg];
        float s1 = fmaxf(sqrtf(r1s), EPS);
        float r2s = r1s / (s1 * s1) + sc;
        float s2 = fmaxf(sqrtf(r2s), EPS);
        float g2 = 1.0f / s2;
        float g1 = 1.0f / (s1 * s2);
        float g0 = g1 / s0;
        float nm = nrm[wg], isq = 1.0f / nm;
        float gn  = nm * g0;
        float gc0 = isq * g0;
        float gc1 = isq * g1;
        const float4* H0 = (const float4*)(h0 + (size_t)wg * 64);
        const float4* H1 = (const float4*)(h1 + (size_t)wg * 64);
        const float4* H2 = (const float4*)(h2 + (size_t)wg * 64);
        float4 av = H0[d4];
        float4 bv = H1[d4];
        float4 cv = H2[d4];
        A0.x += (double)(av.x * gn); A0.y += (double)(av.y * gn);
        A0.z += (double)(av.z * gn); A0.w += (double)(av.w * gn);
        A1.x += (double)((bv.x - av.x) * gc0); A1.y += (double)((bv.y - av.y) * gc0);
        A1.z += (double)((bv.z - av.z) * gc0); A1.w += (double)((bv.w - av.w) * gc0);
        A2.x += (double)((cv.x - bv.x) * gc1); A2.y += (double)((cv.y - bv.y) * gc1);
        A2.z += (double)((cv.z - bv.z) * gc1); A2.w += (double)((cv.w - bv.w) * gc1);
        A3.x += (double)(cq.x * g2); A3.y += (double)(cq.y * g2);
        A3.z += (double)(cq.z * g2); A3.w += (double)(cq.w * g2);
    }
    #pragma unroll
    for (int seg = 0; seg < 4; ++seg) {
        double4 V = (seg == 0) ? A0 : (seg == 1) ? A1 : (seg == 2) ? A2 : A3;
        if (sub == 0) {
            lds[wid * 64 + d4 * 4 + 0] = V.x;
            lds[wid * 64 + d4 * 4 + 1] = V.y;
            lds[wid * 64 + d4 * 4 + 2] = V.z;
            lds[wid * 64 + d4 * 4 + 3] = V.w;
        }
        __syncthreads();
        if (tid < 64)
            partialF[(size_t)blockIdx.x * 256 + seg * 64 + tid] =
                lds[tid] + lds[64 + tid] + lds[128 + tid] + lds[192 + tid];
        __syncthreads();
    }
}

__global__ void reduceP_kernel(const double* __restrict__ partialF, double* __restrict__ mid) {
    int t = threadIdx.x;
    double acc = 0.0;
    for (int j = 0; j < 64; ++j)
        acc += partialF[((size_t)blockIdx.x * 64 + j) * 256 + t];
    mid[(size_t)blockIdx.x * 256 + t] = acc;
}

__global__ void final_kernel(const double* __restrict__ mid, const float* __restrict__ W_lin,
                             const float* __restrict__ b_lin, const float* __restrict__ W_out,
                             const float* __restrict__ b_out, float* __restrict__ out) {
    __shared__ double cs[256];
    __shared__ double hg[64];
    int t = threadIdx.x;  // 256
    double acc = 0.0;
    for (int b = 0; b < 32; ++b) acc += mid[b * 256 + t];
    cs[t] = acc;
    __syncthreads();
    if (t < 64) {
        const double invN = 1.0 / (double)NN;
        double a = (double)b_lin[t];
        for (int k = 0; k < 256; ++k) a += cs[k] * invN * (double)W_lin[t * 256 + k];
        hg[t] = a;
    }
    __syncthreads();
    if (t < 10) {
        double o = (double)b_out[t];
        for (int k = 0; k < 64; ++k) o += hg[k] * (double)W_out[t * 64 + k];
        out[t] = (float)o;
    }
}

extern "C" void kernel_launch(void* const* d_in, const int* in_sizes, int n_in,
                              void* d_out, int out_size, void* d_ws, size_t ws_size,
                              hipStream_t stream) {
    const float* x     = (const float*)d_in[0];
    const int*   src   = (const int*)d_in[1];
    const int*   dst   = (const int*)d_in[2];
    const float* W_emb = (const float*)d_in[3];
    const float* b_emb = (const float*)d_in[4];
    const float* W_lin = (const float*)d_in[5];
    const float* b_lin = (const float*)d_in[6];
    const float* W_out = (const float*)d_in[7];
    const float* b_out = (const float*)d_in[8];
    float* out = (float*)d_out;

    char* ws = (char*)d_ws;
    float*  h0      = (float*)(ws + OFF_H0);
    float*  h1      = (float*)(ws + OFF_H1);
    float*  h2      = (float*)(ws + OFF_H2);
    int*    csrp    = (int*)(ws + OFF_CSRP);
    int*    row_off = (int*)(ws + OFF_ROW);
    float*  nrm     = (float*)(ws + OFF_NRM);
    float*  invd    = (float*)(ws + OFF_INVD);
    float*  hh      = (float*)(ws + OFF_HH);
    float*  q0      = (float*)(ws + OFF_Q0);
    float*  q1      = (float*)(ws + OFF_Q1);
    int*    subdeg  = (int*)(ws + OFF_SUBDEG);
    int*    subrow  = (int*)(ws + OFF_SUBROW);
    int*    subcur  = (int*)(ws + OFF_SUBCUR);
    int*    subcsr  = (int*)(ws + OFF_SUBCSR);
    int*    deg     = (int*)(ws + OFF_DEG);
    int*    bsum    = (int*)(ws + OFF_BSUM);
    int*    boff    = (int*)(ws + OFF_BOFF);
    double* partialF= (double*)(ws + OFF_PARTF);
    double* mid     = (double*)(ws + OFF_MID);

    hipMemsetAsync(subdeg, 0, (size_t)8 * NN * 4, stream);

    const int edgeBlocks = (NE + 255) / 256;            // 6250
    hist8_kernel<<<edgeBlocks, 256, 0, stream>>>(dst, subdeg);
    degnorm_kernel<<<(NN + 255) / 256, 256, 0, stream>>>(subdeg, deg, nrm, invd);

    // scan subdeg[8N] -> subrow (+ copy to subcur)
    const int sb8 = (8 * NN + 511) / 512;               // 1563
    scanA_kernel<<<sb8, 512, 0, stream>>>(subdeg, 8 * NN, subrow, bsum);
    scanB_kernel<<<1, 512, 0, stream>>>(bsum, sb8, boff, subrow + 8 * NN);
    scanC_kernel<<<sb8, 512, 0, stream>>>(subrow, boff, 8 * NN, subcur);
    // scan deg[N] -> row_off
    const int sbN = (NN + 511) / 512;                   // 196
    scanA_kernel<<<sbN, 512, 0, stream>>>(deg, NN, row_off, bsum);
    scanB_kernel<<<1, 512, 0, stream>>>(bsum, sbN, boff, row_off + NN);
    scanC_kernel<<<sbN, 512, 0, stream>>>(row_off, boff, NN, (int*)nullptr);

    fillB_kernel<<<edgeBlocks, 256, 0, stream>>>(src, dst, subcur, subcsr);
    merge_bs_kernel<<<edgeBlocks, 256, 0, stream>>>(row_off, subrow, subcur, subcsr, nrm, csrp);

    embed_kernel<<<(NN + 63) / 64, 256, 0, stream>>>(x, W_emb, b_emb, h0);

    const int nodeBlocks = (NN * 64 + 255) / 256;       // wave per node
    layer0_kernel<<<nodeBlocks, 256, 0, stream>>>(h0, row_off, csrp, nrm, invd, h1, hh, q0);
    layer1_kernel<<<nodeBlocks, 256, 0, stream>>>(h1, row_off, csrp, nrm, invd, h2, q1);
    layer2_fused<<<2048, 256, 0, stream>>>(h0, h1, h2, row_off, csrp, nrm, invd, hh, q0, q1,
                                           partialF);

    reduceP_kernel<<<32, 256, 0, stream>>>(partialF, mid);
    final_kernel<<<1, 256, 0, stream>>>(mid, W_lin, b_lin, W_out, b_out, out);
}

// Round 10
// 404.558 us; speedup vs baseline: 1.1087x; 1.1087x over previous
//
#include <hip/hip_runtime.h>

#define NN 100000
#define NE 1600000

// ---- workspace layout (bytes) ----
// persistent
static constexpr size_t OFF_H0   = 0;                     // [N,64] f32
static constexpr size_t OFF_H1   = 25600000;              // [N,64] f32
static constexpr size_t OFF_H2   = 51200000;              // [N,64] f32
static constexpr size_t OFF_CSRP = 76800000;              // [E] (int src, f32 w) pairs = 12.8MB
static constexpr size_t OFF_ROW  = 89600000;              // [N+1] i32
static constexpr size_t OFF_NRM  = 90000064;              // [N] f32
static constexpr size_t OFF_INVD = 90400064;              // [N] f32
static constexpr size_t OFF_HH   = 90800064;              // [N] f32
static constexpr size_t OFF_Q0   = 91200064;              // [N] f32
static constexpr size_t OFF_Q1   = 91600064;              // [N] f32
static constexpr size_t OFF_SCR  = 92000064;              // union scratch base
// scratch A (CSR build)
static constexpr size_t OFF_SUBDEG = OFF_SCR;             // [8N] i32
static constexpr size_t OFF_SUBCUR = OFF_SCR + 3200000;   // [8N] i32
static constexpr size_t OFF_BSUM   = OFF_SCR + 6400000;   // [<=2048] i32
static constexpr size_t OFF_BOFF   = OFF_SCR + 6408192;   // [<=2048] i32
// scratch B (layers onward) — reuses region after CSR build is done?  NO:
// subcur/subdeg are dead after fillB, but partialF region must not overlap
// anything live.  partialF/mid placed past subcur region to be safe.
static constexpr size_t OFF_PARTF = OFF_SCR + 8388608;    // [2048,256] f64 = 4MB
static constexpr size_t OFF_MID   = OFF_PARTF + 4194304;  // [32,256] f64

// ---- CSR build: XCD-local histogram ----
__global__ void hist8_kernel(const int* __restrict__ dst, int* __restrict__ subdeg) {
    int e = blockIdx.x * 256 + threadIdx.x;
    int g = blockIdx.x & 7;
    if (e < NE) {
        int d = __builtin_nontemporal_load(&dst[e]);
        atomicAdd(&subdeg[g * NN + d], 1);
    }
}

__global__ void degnorm_kernel(const int* __restrict__ subdeg, float* __restrict__ nrm,
                               float* __restrict__ invd) {
    int n = blockIdx.x * 256 + threadIdx.x;
    if (n < NN) {
        int d = 0;
        #pragma unroll
        for (int g = 0; g < 8; ++g) d += subdeg[g * NN + n];
        float df = (float)max(d, 1);
        nrm[n]  = 1.0f / sqrtf(df);
        invd[n] = 1.0f / df;
    }
}

// ---- permuted scan: logical order idx=(n<<3)|g over subdeg[g*NN+n] ----
// The exclusive scan in this order gives each (n,g) sub-segment its FINAL
// position in the global CSR (node-major) -> fillB writes csrp directly,
// no merge pass needed.  row_off[n] = scanned value at (n, g=0).
__global__ void scanPA_kernel(const int* __restrict__ subdeg, int* __restrict__ subcur,
                              int* __restrict__ bsum) {
    __shared__ int wsum[8], wexcl[8];
    int tid = threadIdx.x, lane = tid & 63, wid = tid >> 6;
    int i = blockIdx.x * 512 + tid;
    int v = 0;
    if (i < 8 * NN) v = subdeg[(i & 7) * NN + (i >> 3)];
    int x = v;
    #pragma unroll
    for (int off = 1; off < 64; off <<= 1) {
        int y = __shfl_up(x, off);
        if (lane >= off) x += y;
    }
    if (lane == 63) wsum[wid] = x;
    __syncthreads();
    if (tid == 0) {
        int c = 0;
        #pragma unroll
        for (int j = 0; j < 8; ++j) { wexcl[j] = c; c += wsum[j]; }
        bsum[blockIdx.x] = c;
    }
    __syncthreads();
    if (i < 8 * NN) subcur[(i & 7) * NN + (i >> 3)] = (x - v) + wexcl[wid];
}

__global__ void scanB_kernel(const int* __restrict__ bsum, int nb, int* __restrict__ boff,
                             int* __restrict__ total_out) {
    __shared__ int wsum[8], wexcl[8];
    __shared__ int carry;
    int tid = threadIdx.x, lane = tid & 63, wid = tid >> 6;
    if (tid == 0) carry = 0;
    __syncthreads();
    for (int base = 0; base < nb; base += 512) {
        int i = base + tid;
        int v = (i < nb) ? bsum[i] : 0;
        int x = v;
        #pragma unroll
        for (int off = 1; off < 64; off <<= 1) {
            int y = __shfl_up(x, off);
            if (lane >= off) x += y;
        }
        if (lane == 63) wsum[wid] = x;
        __syncthreads();
        if (tid == 0) {
            int c = 0;
            #pragma unroll
            for (int j = 0; j < 8; ++j) { wexcl[j] = c; c += wsum[j]; }
        }
        __syncthreads();
        if (i < nb) boff[i] = carry + wexcl[wid] + (x - v);
        __syncthreads();
        if (tid == 0) carry += wexcl[7] + wsum[7];
        __syncthreads();
    }
    if (tid == 0) *total_out = carry;
}

__global__ void scanPC_kernel(int* __restrict__ subcur, const int* __restrict__ boff,
                              int* __restrict__ row_off) {
    int i = blockIdx.x * 512 + threadIdx.x;
    if (i < 8 * NN) {
        int g = i & 7, n = i >> 3;
        int r = subcur[g * NN + n] + boff[blockIdx.x];
        subcur[g * NN + n] = r;
        if (g == 0) row_off[n] = r;
    }
}

// direct fill: write (src, nrm[src]) pair at final CSR position
__global__ void fillB_kernel(const int* __restrict__ src, const int* __restrict__ dst,
                             const float* __restrict__ nrm, int* __restrict__ subcur,
                             int* __restrict__ csrp) {
    int e = blockIdx.x * 256 + threadIdx.x;
    int g = blockIdx.x & 7;
    if (e < NE) {
        int d = __builtin_nontemporal_load(&dst[e]);
        int s = __builtin_nontemporal_load(&src[e]);
        int p = atomicAdd(&subcur[g * NN + d], 1);
        int2 pr;
        pr.x = s;
        pr.y = __float_as_int(nrm[s]);
        ((int2*)csrp)[p] = pr;
    }
}

// ---- embed: h0 = x @ W_emb.T + b_emb (rolled k-loop, no spill) ----
#define FMA4(a_, s_, v_)                        \
    a_.x = fmaf((s_), (v_).x, a_.x);            \
    a_.y = fmaf((s_), (v_).y, a_.y);            \
    a_.z = fmaf((s_), (v_).z, a_.z);            \
    a_.w = fmaf((s_), (v_).w, a_.w);

__global__ void embed_kernel(const float* __restrict__ x, const float* __restrict__ W,
                             const float* __restrict__ bias, float* __restrict__ h) {
    __shared__ __align__(16) float xs[64 * 68];
    __shared__ __align__(16) float Wt[64 * 68];   // Wt[k][d] = W[d][k]
    const int tid = threadIdx.x;
    for (int i = tid; i < 64 * 64; i += 256) {
        int d = i >> 6, k = i & 63;
        Wt[k * 68 + d] = W[i];
    }
    const int base = blockIdx.x * 64;
    for (int i = tid; i < 64 * 16; i += 256) {
        int r = i >> 4, c4 = i & 15;
        float4 v = make_float4(0.f, 0.f, 0.f, 0.f);
        if (base + r < NN) v = ((const float4*)x)[(size_t)(base + r) * 16 + c4];
        *(float4*)&xs[r * 68 + c4 * 4] = v;
    }
    __syncthreads();
    const int tn = tid >> 4;
    const int td = tid & 15;
    const float* xr0 = &xs[(tn * 4 + 0) * 68];
    const float* xr1 = &xs[(tn * 4 + 1) * 68];
    const float* xr2 = &xs[(tn * 4 + 2) * 68];
    const float* xr3 = &xs[(tn * 4 + 3) * 68];
    float4 a0 = make_float4(0.f, 0.f, 0.f, 0.f);
    float4 a1 = a0, a2 = a0, a3 = a0;
    #pragma unroll 1
    for (int k0 = 0; k0 < 64; k0 += 4) {
        float4 xa0 = *(const float4*)&xr0[k0];
        float4 xa1 = *(const float4*)&xr1[k0];
        float4 xa2 = *(const float4*)&xr2[k0];
        float4 xa3 = *(const float4*)&xr3[k0];
        float4 w0 = *(const float4*)&Wt[(k0 + 0) * 68 + td * 4];
        float4 w1 = *(const float4*)&Wt[(k0 + 1) * 68 + td * 4];
        float4 w2 = *(const float4*)&Wt[(k0 + 2) * 68 + td * 4];
        float4 w3 = *(const float4*)&Wt[(k0 + 3) * 68 + td * 4];
        FMA4(a0, xa0.x, w0); FMA4(a1, xa1.x, w0); FMA4(a2, xa2.x, w0); FMA4(a3, xa3.x, w0);
        FMA4(a0, xa0.y, w1); FMA4(a1, xa1.y, w1); FMA4(a2, xa2.y, w1); FMA4(a3, xa3.y, w1);
        FMA4(a0, xa0.z, w2); FMA4(a1, xa1.z, w2); FMA4(a2, xa2.z, w2); FMA4(a3, xa3.z, w2);
        FMA4(a0, xa0.w, w3); FMA4(a1, xa1.w, w3); FMA4(a2, xa2.w, w3); FMA4(a3, xa3.w, w3);
    }
    float4 bb = ((const float4*)bias)[td];
    a0.x += bb.x; a0.y += bb.y; a0.z += bb.z; a0.w += bb.w;
    a1.x += bb.x; a1.y += bb.y; a1.z += bb.z; a1.w += bb.w;
    a2.x += bb.x; a2.y += bb.y; a2.z += bb.z; a2.w += bb.w;
    a3.x += bb.x; a3.y += bb.y; a3.z += bb.z; a3.w += bb.w;
    int n0 = base + tn * 4;
    if (n0 + 0 < NN) ((float4*)h)[(size_t)(n0 + 0) * 16 + td] = a0;
    if (n0 + 1 < NN) ((float4*)h)[(size_t)(n0 + 1) * 16 + td] = a1;
    if (n0 + 2 < NN) ((float4*)h)[(size_t)(n0 + 2) * 16 + td] = a2;
    if (n0 + 3 < NN) ((float4*)h)[(size_t)(n0 + 3) * 16 + td] = a3;
}

// round-8 gather: per-lane full-row loads, 8 outstanding gathers per iteration
__device__ __forceinline__ float gather_pair(const float* __restrict__ h,
                                             const int* __restrict__ csrp,
                                             int start, int end, int lane) {
    float a0 = 0.f, a1 = 0.f, a2 = 0.f, a3 = 0.f;
    int i = start;
    for (; i + 8 <= end; i += 8) {
        int s0 = csrp[2*i+0];  float w0 = __int_as_float(csrp[2*i+1]);
        int s1 = csrp[2*i+2];  float w1 = __int_as_float(csrp[2*i+3]);
        int s2 = csrp[2*i+4];  float w2 = __int_as_float(csrp[2*i+5]);
        int s3 = csrp[2*i+6];  float w3 = __int_as_float(csrp[2*i+7]);
        int s4 = csrp[2*i+8];  float w4 = __int_as_float(csrp[2*i+9]);
        int s5 = csrp[2*i+10]; float w5 = __int_as_float(csrp[2*i+11]);
        int s6 = csrp[2*i+12]; float w6 = __int_as_float(csrp[2*i+13]);
        int s7 = csrp[2*i+14]; float w7 = __int_as_float(csrp[2*i+15]);
        a0 = fmaf(h[(size_t)s0 * 64 + lane], w0, a0);
        a1 = fmaf(h[(size_t)s1 * 64 + lane], w1, a1);
        a2 = fmaf(h[(size_t)s2 * 64 + lane], w2, a2);
        a3 = fmaf(h[(size_t)s3 * 64 + lane], w3, a3);
        a0 = fmaf(h[(size_t)s4 * 64 + lane], w4, a0);
        a1 = fmaf(h[(size_t)s5 * 64 + lane], w5, a1);
        a2 = fmaf(h[(size_t)s6 * 64 + lane], w6, a2);
        a3 = fmaf(h[(size_t)s7 * 64 + lane], w7, a3);
    }
    for (; i + 2 <= end; i += 2) {
        int s0 = csrp[2*i+0]; float w0 = __int_as_float(csrp[2*i+1]);
        int s1 = csrp[2*i+2]; float w1 = __int_as_float(csrp[2*i+3]);
        a0 = fmaf(h[(size_t)s0 * 64 + lane], w0, a0);
        a1 = fmaf(h[(size_t)s1 * 64 + lane], w1, a1);
    }
    if (i < end) {
        int s0 = csrp[2*i+0]; float w0 = __int_as_float(csrp[2*i+1]);
        a0 = fmaf(h[(size_t)s0 * 64 + lane], w0, a0);
    }
    return (a0 + a1) + (a2 + a3);
}

// layer0: gather c0 (not stored); h1 = h0 + c0*nm; hh=||h0*nm||^2, q0=||c0||^2
__global__ void layer0_kernel(const float* __restrict__ h0, const int* __restrict__ row_off,
                              const int* __restrict__ csrp, const float* __restrict__ nrm,
                              const float* __restrict__ invd, float* __restrict__ h1,
                              float* __restrict__ hh, float* __restrict__ q0) {
    int wg = __builtin_amdgcn_readfirstlane((blockIdx.x * 256 + threadIdx.x) >> 6);
    int lane = threadIdx.x & 63;
    if (wg >= NN) return;
    float cv = gather_pair(h0, csrp, row_off[wg], row_off[wg + 1], lane) * invd[wg];
    float nm = nrm[wg];
    size_t o = (size_t)wg * 64 + lane;
    float hv = h0[o];
    float hn = hv * nm;
    h1[o] = fmaf(cv, nm, hv);
    float sh = hn * hn, sc = cv * cv;
    #pragma unroll
    for (int off = 32; off >= 1; off >>= 1) {
        sh += __shfl_xor(sh, off);
        sc += __shfl_xor(sc, off);
    }
    if (lane == 0) { hh[wg] = sh; q0[wg] = sc; }
}

// layer1: gather c1 (not stored); h2 = h1 + c1*nm; q1=||c1||^2
__global__ void layer1_kernel(const float* __restrict__ h1, const int* __restrict__ row_off,
                              const int* __restrict__ csrp, const float* __restrict__ nrm,
                              const float* __restrict__ invd, float* __restrict__ h2,
                              float* __restrict__ q1) {
    int wg = __builtin_amdgcn_readfirstlane((blockIdx.x * 256 + threadIdx.x) >> 6);
    int lane = threadIdx.x & 63;
    if (wg >= NN) return;
    float cv = gather_pair(h1, csrp, row_off[wg], row_off[wg + 1], lane) * invd[wg];
    float nm = nrm[wg];
    size_t o = (size_t)wg * 64 + lane;
    float hv = h1[o];
    h2[o] = fmaf(cv, nm, hv);
    float sc = cv * cv;
    #pragma unroll
    for (int off = 32; off >= 1; off >>= 1) sc += __shfl_xor(sc, off);
    if (lane == 0) q1[wg] = sc;
}

// layer2 fused with weighted colsum.  Hot-loop accumulators are f32 (each wave
// sums only ~12 nodes of O(1)-magnitude normalized values; the final /N mean
// makes the f32 partial error ~1e-9 in the output).  f64 from block level up.
__global__ void layer2_fused(const float* __restrict__ h0, const float* __restrict__ h1,
                             const float* __restrict__ h2, const int* __restrict__ row_off,
                             const int* __restrict__ csrp, const float* __restrict__ nrm,
                             const float* __restrict__ invd, const float* __restrict__ hh,
                             const float* __restrict__ q0, const float* __restrict__ q1,
                             double* __restrict__ partialF) {
    __shared__ double lds[256];
    int tid = threadIdx.x, lane = tid & 63, wid = tid >> 6;
    float A0 = 0.f, A1 = 0.f, A2 = 0.f, A3 = 0.f;
    const float EPS = 1e-12f;
    for (int nb = blockIdx.x * 4 + wid; nb < NN; nb += gridDim.x * 4) {
        int wg = __builtin_amdgcn_readfirstlane(nb);
        float cv = gather_pair(h2, csrp, row_off[wg], row_off[wg + 1], lane) * invd[wg];
        float sc = cv * cv;
        #pragma unroll
        for (int off = 32; off >= 1; off >>= 1) sc += __shfl_xor(sc, off);
        float n0s = hh[wg] + q0[wg];
        float s0 = fmaxf(sqrtf(n0s), EPS);
        float r1s = n0s / (s0 * s0) + q1[wg];
        float s1 = fmaxf(sqrtf(r1s), EPS);
        float r2s = r1s / (s1 * s1) + sc;
        float s2 = fmaxf(sqrtf(r2s), EPS);
        float g2 = 1.0f / s2;
        float g1 = 1.0f / (s1 * s2);
        float g0 = g1 / s0;
        float nm = nrm[wg];
        float isq = 1.0f / nm;
        size_t o = (size_t)wg * 64 + lane;
        float h0v = h0[o], h1v = h1[o], h2v = h2[o];
        A0 = fmaf(h0v * nm, g0, A0);
        A1 = fmaf((h1v - h0v) * isq, g0, A1);
        A2 = fmaf((h2v - h1v) * isq, g1, A2);
        A3 = fmaf(cv, g2, A3);
    }
    #pragma unroll
    for (int seg = 0; seg < 4; ++seg) {
        float v = (seg == 0) ? A0 : (seg == 1) ? A1 : (seg == 2) ? A2 : A3;
        lds[tid] = (double)v;
        __syncthreads();
        if (wid == 0)
            partialF[(size_t)blockIdx.x * 256 + seg * 64 + lane] =
                lds[lane] + lds[64 + lane] + lds[128 + lane] + lds[192 + lane];
        __syncthreads();
    }
}

__global__ void reduceP_kernel(const double* __restrict__ partialF, double* __restrict__ mid) {
    int t = threadIdx.x;
    double acc = 0.0;
    for (int j = 0; j < 64; ++j)
        acc += partialF[((size_t)blockIdx.x * 64 + j) * 256 + t];
    mid[(size_t)blockIdx.x * 256 + t] = acc;
}

__global__ void final_kernel(const double* __restrict__ mid, const float* __restrict__ W_lin,
                             const float* __restrict__ b_lin, const float* __restrict__ W_out,
                             const float* __restrict__ b_out, float* __restrict__ out) {
    __shared__ double cs[256];
    __shared__ double hg[64];
    int t = threadIdx.x;  // 256
    double acc = 0.0;
    for (int b = 0; b < 32; ++b) acc += mid[b * 256 + t];
    cs[t] = acc;
    __syncthreads();
    if (t < 64) {
        const double invN = 1.0 / (double)NN;
        double a = (double)b_lin[t];
        for (int k = 0; k < 256; ++k) a += cs[k] * invN * (double)W_lin[t * 256 + k];
        hg[t] = a;
    }
    __syncthreads();
    if (t < 10) {
        double o = (double)b_out[t];
        for (int k = 0; k < 64; ++k) o += hg[k] * (double)W_out[t * 64 + k];
        out[t] = (float)o;
    }
}

extern "C" void kernel_launch(void* const* d_in, const int* in_sizes, int n_in,
                              void* d_out, int out_size, void* d_ws, size_t ws_size,
                              hipStream_t stream) {
    const float* x     = (const float*)d_in[0];
    const int*   src   = (const int*)d_in[1];
    const int*   dst   = (const int*)d_in[2];
    const float* W_emb = (const float*)d_in[3];
    const float* b_emb = (const float*)d_in[4];
    const float* W_lin = (const float*)d_in[5];
    const float* b_lin = (const float*)d_in[6];
    const float* W_out = (const float*)d_in[7];
    const float* b_out = (const float*)d_in[8];
    float* out = (float*)d_out;

    char* ws = (char*)d_ws;
    float*  h0      = (float*)(ws + OFF_H0);
    float*  h1      = (float*)(ws + OFF_H1);
    float*  h2      = (float*)(ws + OFF_H2);
    int*    csrp    = (int*)(ws + OFF_CSRP);
    int*    row_off = (int*)(ws + OFF_ROW);
    float*  nrm     = (float*)(ws + OFF_NRM);
    float*  invd    = (float*)(ws + OFF_INVD);
    float*  hh      = (float*)(ws + OFF_HH);
    float*  q0      = (float*)(ws + OFF_Q0);
    float*  q1      = (float*)(ws + OFF_Q1);
    int*    subdeg  = (int*)(ws + OFF_SUBDEG);
    int*    subcur  = (int*)(ws + OFF_SUBCUR);
    int*    bsum    = (int*)(ws + OFF_BSUM);
    int*    boff    = (int*)(ws + OFF_BOFF);
    double* partialF= (double*)(ws + OFF_PARTF);
    double* mid     = (double*)(ws + OFF_MID);

    hipMemsetAsync(subdeg, 0, (size_t)8 * NN * 4, stream);

    const int edgeBlocks = (NE + 255) / 256;            // 6250
    hist8_kernel<<<edgeBlocks, 256, 0, stream>>>(dst, subdeg);
    degnorm_kernel<<<(NN + 255) / 256, 256, 0, stream>>>(subdeg, nrm, invd);

    // permuted scan over (n,g)-ordered subdeg -> final CSR offsets in subcur
    const int sb8 = (8 * NN + 511) / 512;               // 1563
    scanPA_kernel<<<sb8, 512, 0, stream>>>(subdeg, subcur, bsum);
    scanB_kernel<<<1, 512, 0, stream>>>(bsum, sb8, boff, row_off + NN);  // row_off[NN]=NE
    scanPC_kernel<<<sb8, 512, 0, stream>>>(subcur, boff, row_off);

    fillB_kernel<<<edgeBlocks, 256, 0, stream>>>(src, dst, nrm, subcur, csrp);

    embed_kernel<<<(NN + 63) / 64, 256, 0, stream>>>(x, W_emb, b_emb, h0);

    const int nodeBlocks = (NN * 64 + 255) / 256;       // wave per node
    layer0_kernel<<<nodeBlocks, 256, 0, stream>>>(h0, row_off, csrp, nrm, invd, h1, hh, q0);
    layer1_kernel<<<nodeBlocks, 256, 0, stream>>>(h1, row_off, csrp, nrm, invd, h2, q1);
    layer2_fused<<<2048, 256, 0, stream>>>(h0, h1, h2, row_off, csrp, nrm, invd, hh, q0, q1,
                                           partialF);

    reduceP_kernel<<<32, 256, 0, stream>>>(partialF, mid);
    final_kernel<<<1, 256, 0, stream>>>(mid, W_lin, b_lin, W_out, b_out, out);
}